// Round 1
// baseline (5657.581 us; speedup 1.0000x reference)
//
#include <hip/hip_runtime.h>
#include <math.h>

#define NV 20000
#define NB 4
#define CF 64
#define VX 64

// ---------------- CSR construction (dst-sorted) ----------------

__global__ void hist_dst_kernel(const int* __restrict__ dst, int E, int* __restrict__ cnt) {
  int i = blockIdx.x * blockDim.x + threadIdx.x;
  if (i < E) atomicAdd(&cnt[dst[i]], 1);
}

// single-block exclusive scan over cnt -> rowp; also dinv[n]=1/sqrt(indeg+1)
__global__ void scan_kernel(const int* __restrict__ cnt, int* __restrict__ rowp,
                            float* __restrict__ dinv, int n) {
  __shared__ int sdata[1024];
  __shared__ int run_s;
  if (threadIdx.x == 0) run_s = 0;
  __syncthreads();
  for (int base = 0; base < n; base += 1024) {
    int i = base + (int)threadIdx.x;
    int v = (i < n) ? cnt[i] : 0;
    sdata[threadIdx.x] = v;
    __syncthreads();
    int run = run_s;
    for (int ofs = 1; ofs < 1024; ofs <<= 1) {
      int t = (threadIdx.x >= (unsigned)ofs) ? sdata[threadIdx.x - ofs] : 0;
      __syncthreads();
      sdata[threadIdx.x] += t;
      __syncthreads();
    }
    if (i < n) {
      rowp[i] = run + sdata[threadIdx.x] - v;
      dinv[i] = 1.0f / sqrtf((float)(v + 1));
    }
    if (threadIdx.x == 1023) run_s = run + sdata[1023];
    __syncthreads();
  }
  if (threadIdx.x == 0) rowp[n] = run_s;
}

__global__ void fill_csr_kernel(const int* __restrict__ src, const int* __restrict__ dst, int E,
                                const int* __restrict__ rowp, int* __restrict__ cnt2,
                                int* __restrict__ esrc) {
  int i = blockIdx.x * blockDim.x + threadIdx.x;
  if (i < E) {
    int d = dst[i];
    int pos = rowp[d] + atomicAdd(&cnt2[d], 1);
    esrc[pos] = src[i];
  }
}

// ---------------- constant feature sample ----------------
// vn == -1 exactly (batch-min of identical copies), /1.5 -> constant grid point.
__global__ void vfeat_kernel(const float* __restrict__ feat, float* __restrict__ vfeat) {
  int t = blockIdx.x * blockDim.x + threadIdx.x; // 0..NB*CF-1
  if (t >= NB * CF) return;
  float c = (2.0f * 0.0f / 1e-6f - 1.0f) / 1.5f;          // matches reference fp32 math
  float pos = (c + 1.0f) * 0.5f * (float)(VX - 1);
  pos = fminf(fmaxf(pos, 0.0f), (float)(VX - 1));
  float f0 = floorf(pos);
  float w = pos - f0;
  int i0 = (int)f0;
  int i1 = i0 + 1; if (i1 > VX - 1) i1 = VX - 1;
  const float* base = feat + (size_t)t * VX * VX * VX;
  float wz[2] = {1.0f - w, w};
  int   iz[2] = {i0, i1};
  float acc = 0.0f;
  #pragma unroll
  for (int a = 0; a < 2; ++a)
    #pragma unroll
    for (int b = 0; b < 2; ++b)
      #pragma unroll
      for (int d = 0; d < 2; ++d)
        acc += wz[a] * wz[b] * wz[d] * base[(size_t)iz[a] * VX * VX + iz[b] * VX + iz[d]];
  vfeat[t] = acc;
}

// encc[b][j] = sum_c vfeat[b][c] * W1[3+c][j] + b1[j]
__global__ void encconst_kernel(const float* __restrict__ vfeat, const float* __restrict__ W1,
                                const float* __restrict__ b1, float* __restrict__ encc) {
  int idx = blockIdx.x * blockDim.x + threadIdx.x;
  if (idx >= NB * 256) return;
  int b = idx >> 8, j = idx & 255;
  float acc = b1[j];
  #pragma unroll 8
  for (int c = 0; c < CF; ++c) acc += vfeat[b * CF + c] * W1[(3 + c) * 256 + j];
  encc[idx] = acc;
}

// x1[n][j] = relu(v[n].W1[0:3][j] + encc_b[j])
__global__ void enc1_kernel(const float* __restrict__ verts, const float* __restrict__ W1,
                            const float* __restrict__ encc_b, float* __restrict__ out) {
  int idx = blockIdx.x * blockDim.x + threadIdx.x;
  if (idx >= NV * 256) return;
  int n = idx >> 8, j = idx & 255;
  float acc = encc_b[j]
            + verts[n * 3 + 0] * W1[0 * 256 + j]
            + verts[n * 3 + 1] * W1[1 * 256 + j]
            + verts[n * 3 + 2] * W1[2 * 256 + j];
  out[idx] = fmaxf(acc, 0.0f);
}

// ---------------- fp32 tiled GEMM: C[M,N] = A[M,K] @ W[K,N] (+bias)(+relu) ----------------
// 64x64 tile, BK=16, 256 threads, 4x4 per thread. K%16==0, N%64==0 (guaranteed by caller).
__launch_bounds__(256, 2)
__global__ void gemm_kernel(const float* __restrict__ A, const float* __restrict__ W,
                            const float* __restrict__ bias, float* __restrict__ C,
                            int M, int N, int K, int do_relu, int do_bias) {
  __shared__ float As[64][17];   // [m][k] padded
  __shared__ float Bs[16][64];   // [k][n]
  int tid = threadIdx.x;
  int tx = tid & 15;
  int ty = tid >> 4;
  int mbase = blockIdx.y * 64;
  int nbase = blockIdx.x * 64;

  float acc[4][4];
  #pragma unroll
  for (int i = 0; i < 4; ++i)
    #pragma unroll
    for (int j = 0; j < 4; ++j) acc[i][j] = 0.f;

  int la_m = tid >> 2;          // 0..63
  int la_k = (tid & 3) << 2;    // 0,4,8,12
  int lb_k = tid >> 4;          // 0..15
  int lb_n = (tid & 15) << 2;   // 0..60
  int gm = mbase + la_m;

  for (int kb = 0; kb < K; kb += 16) {
    float4 av;
    if (gm < M) av = *(const float4*)(A + (size_t)gm * K + kb + la_k);
    else av = make_float4(0.f, 0.f, 0.f, 0.f);
    float4 bv = *(const float4*)(W + (size_t)(kb + lb_k) * N + nbase + lb_n);
    __syncthreads();
    As[la_m][la_k + 0] = av.x; As[la_m][la_k + 1] = av.y;
    As[la_m][la_k + 2] = av.z; As[la_m][la_k + 3] = av.w;
    *(float4*)(&Bs[lb_k][lb_n]) = bv;
    __syncthreads();
    #pragma unroll
    for (int k = 0; k < 16; ++k) {
      float a0 = As[ty * 4 + 0][k], a1 = As[ty * 4 + 1][k];
      float a2 = As[ty * 4 + 2][k], a3 = As[ty * 4 + 3][k];
      float b0 = Bs[k][tx * 4 + 0], b1 = Bs[k][tx * 4 + 1];
      float b2 = Bs[k][tx * 4 + 2], b3 = Bs[k][tx * 4 + 3];
      acc[0][0] += a0 * b0; acc[0][1] += a0 * b1; acc[0][2] += a0 * b2; acc[0][3] += a0 * b3;
      acc[1][0] += a1 * b0; acc[1][1] += a1 * b1; acc[1][2] += a1 * b2; acc[1][3] += a1 * b3;
      acc[2][0] += a2 * b0; acc[2][1] += a2 * b1; acc[2][2] += a2 * b2; acc[2][3] += a2 * b3;
      acc[3][0] += a3 * b0; acc[3][1] += a3 * b1; acc[3][2] += a3 * b2; acc[3][3] += a3 * b3;
    }
  }

  float bj[4] = {0.f, 0.f, 0.f, 0.f};
  if (do_bias) {
    bj[0] = bias[nbase + tx * 4 + 0]; bj[1] = bias[nbase + tx * 4 + 1];
    bj[2] = bias[nbase + tx * 4 + 2]; bj[3] = bias[nbase + tx * 4 + 3];
  }
  #pragma unroll
  for (int i = 0; i < 4; ++i) {
    int m = mbase + ty * 4 + i;
    if (m < M) {
      float4 o;
      o.x = acc[i][0] + bj[0]; o.y = acc[i][1] + bj[1];
      o.z = acc[i][2] + bj[2]; o.w = acc[i][3] + bj[3];
      if (do_relu) {
        o.x = fmaxf(o.x, 0.f); o.y = fmaxf(o.y, 0.f);
        o.z = fmaxf(o.z, 0.f); o.w = fmaxf(o.w, 0.f);
      }
      *(float4*)(C + (size_t)m * N + nbase + tx * 4) = o;
    }
  }
}

// out[n][j] = relu(dinv[n]*(h[n][j]*dinv[n] + sum_src h[src][j]*dinv[src]) + b[j])
__global__ void gcn_epilogue_kernel(const float* __restrict__ h2, const float* __restrict__ bias,
                                    const float* __restrict__ dinv, const int* __restrict__ rowp,
                                    const int* __restrict__ esrc, float* __restrict__ out,
                                    int lc /* log2(Cout) */) {
  int idx = blockIdx.x * blockDim.x + threadIdx.x;
  int Cout = 1 << lc;
  if (idx >= NV * Cout) return;
  int n = idx >> lc;
  int j = idx & (Cout - 1);
  float dn = dinv[n];
  float acc = h2[idx] * dn;
  int s = rowp[n], e = rowp[n + 1];
  for (int t = s; t < e; ++t) {
    int src = esrc[t];
    acc += h2[(size_t)src * Cout + j] * dinv[src];
  }
  out[idx] = fmaxf(acc * dn + bias[j], 0.f);
}

// final: out[n][k] = verts[n][k] + clip(tanh(d[n].hW3[:,k] + hb3[k]), -2.5, 2.5)
__global__ void head3_kernel(const float* __restrict__ d, const float* __restrict__ hW3,
                             const float* __restrict__ hb3, const float* __restrict__ verts,
                             float* __restrict__ out) {
  int idx = blockIdx.x * blockDim.x + threadIdx.x;
  if (idx >= NV * 3) return;
  int n = idx / 3;
  int k = idx - n * 3;
  float acc = hb3[k];
  #pragma unroll 8
  for (int c = 0; c < 64; ++c) acc += d[n * 64 + c] * hW3[c * 3 + k];
  float t = tanhf(acc);
  t = fminf(fmaxf(t, -2.5f), 2.5f);
  out[idx] = verts[idx] + t;
}

// ---------------- launch ----------------

static inline void launch_gemm(const float* A, const float* W, const float* bias, float* C,
                               int M, int N, int K, int relu, int has_bias, hipStream_t stream) {
  dim3 grid(N / 64, (M + 63) / 64);
  gemm_kernel<<<grid, 256, 0, stream>>>(A, W, bias, C, M, N, K, relu, has_bias);
}

extern "C" void kernel_launch(void* const* d_in, const int* in_sizes, int n_in,
                              void* d_out, int out_size, void* d_ws, size_t ws_size,
                              hipStream_t stream) {
  const float* features = (const float*)d_in[0];
  const float* vertices = (const float*)d_in[1];
  const int* edge_index = (const int*)d_in[2];
  const int E = in_sizes[2] / 2;
  const int* esrc_in = edge_index;       // edge_index[0] = src
  const int* edst_in = edge_index + E;   // edge_index[1] = dst
  const float* enc_W1 = (const float*)d_in[3];
  const float* enc_b1 = (const float*)d_in[4];
  const float* enc_W2 = (const float*)d_in[5];
  const float* enc_b2 = (const float*)d_in[6];
  const float* gW[6]; const float* gb[6];
  for (int i = 0; i < 6; ++i) { gW[i] = (const float*)d_in[7 + 2 * i]; gb[i] = (const float*)d_in[8 + 2 * i]; }
  const float* hW1 = (const float*)d_in[19]; const float* hb1 = (const float*)d_in[20];
  const float* hW2 = (const float*)d_in[21]; const float* hb2 = (const float*)d_in[22];
  const float* hW3 = (const float*)d_in[23]; const float* hb3 = (const float*)d_in[24];

  char* ws = (char*)d_ws;
  size_t off = 0;
  auto alloc = [&](size_t bytes) -> void* {
    void* p = (void*)(ws + off);
    off += (bytes + 255) & ~(size_t)255;
    return p;
  };
  float* bufA  = (float*)alloc((size_t)NV * 1024 * sizeof(float));
  float* bufB  = (float*)alloc((size_t)NV * 1024 * sizeof(float));
  float* dinv  = (float*)alloc(NV * sizeof(float));
  float* vfeat = (float*)alloc(NB * CF * sizeof(float));
  float* encc  = (float*)alloc(NB * 256 * sizeof(float));
  int* cnt  = (int*)alloc(NV * sizeof(int));
  int* rowp = (int*)alloc((NV + 1) * sizeof(int));
  int* cnt2 = (int*)alloc(NV * sizeof(int));
  int* esrc = (int*)alloc((size_t)E * sizeof(int));

  hipMemsetAsync(cnt,  0, NV * sizeof(int), stream);
  hipMemsetAsync(cnt2, 0, NV * sizeof(int), stream);
  hist_dst_kernel<<<(E + 255) / 256, 256, 0, stream>>>(edst_in, E, cnt);
  scan_kernel<<<1, 1024, 0, stream>>>(cnt, rowp, dinv, NV);
  fill_csr_kernel<<<(E + 255) / 256, 256, 0, stream>>>(esrc_in, edst_in, E, rowp, cnt2, esrc);
  vfeat_kernel<<<1, 256, 0, stream>>>(features, vfeat);
  encconst_kernel<<<NB, 256, 0, stream>>>(vfeat, enc_W1, enc_b1, encc);

  const int gin[6]  = {128, 256, 512, 1024, 512, 256};
  const int gout[6] = {256, 512, 1024, 512, 256, 128};
  const int glc[6]  = {8, 9, 10, 9, 8, 7};

  for (int b = 0; b < NB; ++b) {
    // enc layer 1 -> bufA [NV,256]
    enc1_kernel<<<(NV * 256 + 255) / 256, 256, 0, stream>>>(vertices, enc_W1, encc + b * 256, bufA);
    // enc layer 2 -> bufB [NV,128]
    launch_gemm(bufA, enc_W2, enc_b2, bufB, NV, 128, 256, 1, 1, stream);

    float* x = bufB;  // current activation
    float* h = bufA;  // gemm output / scratch
    for (int i = 0; i < 6; ++i) {
      launch_gemm(x, gW[i], nullptr, h, NV, gout[i], gin[i], 0, 0, stream);
      int total = NV * gout[i];
      gcn_epilogue_kernel<<<(total + 255) / 256, 256, 0, stream>>>(h, gb[i], dinv, rowp, esrc, x, glc[i]);
    }
    // head: x=bufB [NV,128]
    launch_gemm(x, hW1, hb1, h, NV, 128, 128, 1, 1, stream);  // h=bufA [NV,128]
    launch_gemm(h, hW2, hb2, x, NV, 64, 128, 1, 1, stream);   // x=bufB [NV,64]
    head3_kernel<<<(NV * 3 + 255) / 256, 256, 0, stream>>>(x, hW3, hb3, vertices,
                                                           (float*)d_out + (size_t)b * NV * 3);
  }
}

// Round 2
// 2177.419 us; speedup vs baseline: 2.5983x; 2.5983x over previous
//
#include <hip/hip_runtime.h>
#include <math.h>

#define NV 20000
#define NV_PAD 20096   // 157 * 128
#define NB 4
#define CF 64
#define VX 64

typedef short short8 __attribute__((ext_vector_type(8)));
typedef float floatx4 __attribute__((ext_vector_type(4)));

__device__ __forceinline__ float bf2f(unsigned int h) {
  return __uint_as_float(h << 16);
}
__device__ __forceinline__ unsigned short f2bf(float f) {
  unsigned int u = __float_as_uint(f);
  u += 0x7fffu + ((u >> 16) & 1u);   // round-to-nearest-even
  return (unsigned short)(u >> 16);
}

// ---------------- CSR construction (dst-sorted) ----------------

__global__ void hist_dst_kernel(const int* __restrict__ dst, int E, int* __restrict__ cnt) {
  int i = blockIdx.x * blockDim.x + threadIdx.x;
  if (i < E) atomicAdd(&cnt[dst[i]], 1);
}

__global__ void scan_kernel(const int* __restrict__ cnt, int* __restrict__ rowp,
                            float* __restrict__ dinv, int n) {
  __shared__ int sdata[1024];
  __shared__ int run_s;
  if (threadIdx.x == 0) run_s = 0;
  __syncthreads();
  for (int base = 0; base < n; base += 1024) {
    int i = base + (int)threadIdx.x;
    int v = (i < n) ? cnt[i] : 0;
    sdata[threadIdx.x] = v;
    __syncthreads();
    int run = run_s;
    for (int ofs = 1; ofs < 1024; ofs <<= 1) {
      int t = (threadIdx.x >= (unsigned)ofs) ? sdata[threadIdx.x - ofs] : 0;
      __syncthreads();
      sdata[threadIdx.x] += t;
      __syncthreads();
    }
    if (i < n) {
      rowp[i] = run + sdata[threadIdx.x] - v;
      dinv[i] = 1.0f / sqrtf((float)(v + 1));
    }
    if (threadIdx.x == 1023) run_s = run + sdata[1023];
    __syncthreads();
  }
  if (threadIdx.x == 0) rowp[n] = run_s;
}

__global__ void fill_csr_kernel(const int* __restrict__ src, const int* __restrict__ dst, int E,
                                const int* __restrict__ rowp, int* __restrict__ cnt2,
                                int* __restrict__ esrc) {
  int i = blockIdx.x * blockDim.x + threadIdx.x;
  if (i < E) {
    int d = dst[i];
    int pos = rowp[d] + atomicAdd(&cnt2[d], 1);
    esrc[pos] = src[i];
  }
}

// ---------------- constant feature sample ----------------
// vn == -1 exactly (batch-min of identical copies), /1.5 -> constant grid point.
__global__ void vfeat_kernel(const float* __restrict__ feat, float* __restrict__ vfeat) {
  int t = blockIdx.x * blockDim.x + threadIdx.x;
  if (t >= NB * CF) return;
  float c = (2.0f * 0.0f / 1e-6f - 1.0f) / 1.5f;
  float pos = (c + 1.0f) * 0.5f * (float)(VX - 1);
  pos = fminf(fmaxf(pos, 0.0f), (float)(VX - 1));
  float f0 = floorf(pos);
  float w = pos - f0;
  int i0 = (int)f0;
  int i1 = i0 + 1; if (i1 > VX - 1) i1 = VX - 1;
  const float* base = feat + (size_t)t * VX * VX * VX;
  float wz[2] = {1.0f - w, w};
  int   iz[2] = {i0, i1};
  float acc = 0.0f;
  #pragma unroll
  for (int a = 0; a < 2; ++a)
    #pragma unroll
    for (int b = 0; b < 2; ++b)
      #pragma unroll
      for (int d = 0; d < 2; ++d)
        acc += wz[a] * wz[b] * wz[d] * base[(size_t)iz[a] * VX * VX + iz[b] * VX + iz[d]];
  vfeat[t] = acc;
}

__global__ void encconst_kernel(const float* __restrict__ vfeat, const float* __restrict__ W1,
                                const float* __restrict__ b1, float* __restrict__ encc) {
  int idx = blockIdx.x * blockDim.x + threadIdx.x;
  if (idx >= NB * 256) return;
  int b = idx >> 8, j = idx & 255;
  float acc = b1[j];
  #pragma unroll 8
  for (int c = 0; c < CF; ++c) acc += vfeat[b * CF + c] * W1[(3 + c) * 256 + j];
  encc[idx] = acc;
}

// x1[n][j] = relu(v[n].W1[0:3][j] + encc_b[j]) -> bf16
__global__ void enc1_kernel(const float* __restrict__ verts, const float* __restrict__ W1,
                            const float* __restrict__ encc_b, unsigned short* __restrict__ out) {
  int idx = blockIdx.x * blockDim.x + threadIdx.x;
  if (idx >= NV * 256) return;
  int n = idx >> 8, j = idx & 255;
  float acc = encc_b[j]
            + verts[n * 3 + 0] * W1[0 * 256 + j]
            + verts[n * 3 + 1] * W1[1 * 256 + j]
            + verts[n * 3 + 2] * W1[2 * 256 + j];
  out[idx] = f2bf(fmaxf(acc, 0.0f));
}

// weight prep: W[K,N] fp32 -> Wt[n*K + k] bf16 (transposed)
__global__ void wprep_kernel(const float* __restrict__ W, unsigned short* __restrict__ Wt,
                             int K, int N) {
  int idx = blockIdx.x * blockDim.x + threadIdx.x;
  if (idx >= K * N) return;
  int k = idx / N;
  int n = idx - k * N;
  Wt[(size_t)n * K + k] = f2bf(W[idx]);
}

// ---------------- bf16 MFMA GEMM (m97-style gemm_bt) ----------------
// C[M,N] = A[M,K] @ Bt[N,K]^T ; M fixed NV_PAD ; 128x128 tile, BK=32, 4 waves.
// flags: 1=bias, 2=relu, 4=rowscale(dinv[m])
#define BM 128
#define BN 128
#define BK 32

__launch_bounds__(256, 2)
__global__ void gemm_bt_kernel(const unsigned short* __restrict__ A,
                               const unsigned short* __restrict__ Bt,
                               const float* __restrict__ bias,
                               const float* __restrict__ rowscale,
                               unsigned short* __restrict__ C,
                               int K, int Nreal, int flags) {
  __shared__ unsigned short As[BM * BK];  // [m][k], row = 32 elems = 64 B
  __shared__ unsigned short Bs[BN * BK];  // [n][k]
  int tid = threadIdx.x;
  int wave = tid >> 6, lane = tid & 63;
  int mbase = blockIdx.y * BM;
  int nbase = blockIdx.x * BN;
  int wm = (wave >> 1) * 64, wn = (wave & 1) * 64;

  floatx4 acc[4][4] = {};

  const int rowS = wave * 16 + (lane >> 2);   // staging row (+ p*64)
  const int kseg = (lane & 3) * 8;            // staging k offset (elements)
  const int fr = lane & 15, fq = lane >> 4;   // fragment row / quad

  for (int kb = 0; kb < K; kb += BK) {
    #pragma unroll
    for (int p = 0; p < 2; ++p) {
      const unsigned short* ga = A + (size_t)(mbase + rowS + p * 64) * K + kb + kseg;
      __builtin_amdgcn_global_load_lds(
          (const __attribute__((address_space(1))) void*)ga,
          (__attribute__((address_space(3))) void*)(As + wave * 512 + p * 2048), 16, 0, 0);
      const unsigned short* gb = Bt + (size_t)(nbase + rowS + p * 64) * K + kb + kseg;
      __builtin_amdgcn_global_load_lds(
          (const __attribute__((address_space(1))) void*)gb,
          (__attribute__((address_space(3))) void*)(Bs + wave * 512 + p * 2048), 16, 0, 0);
    }
    __syncthreads();
    short8 af[4], bf[4];
    #pragma unroll
    for (int i = 0; i < 4; ++i)
      af[i] = *(const short8*)(As + (wm + i * 16 + fr) * BK + fq * 8);
    #pragma unroll
    for (int j = 0; j < 4; ++j)
      bf[j] = *(const short8*)(Bs + (wn + j * 16 + fr) * BK + fq * 8);
    #pragma unroll
    for (int i = 0; i < 4; ++i)
      #pragma unroll
      for (int j = 0; j < 4; ++j)
        acc[i][j] = __builtin_amdgcn_mfma_f32_16x16x32_bf16(af[i], bf[j], acc[i][j], 0, 0, 0);
    __syncthreads();
  }

  // epilogue: C/D layout col = lane&15, row = (lane>>4)*4 + r
  #pragma unroll
  for (int j = 0; j < 4; ++j) {
    int n = nbase + wn + j * 16 + fr;
    if (n >= Nreal) continue;
    float bv = (flags & 1) ? bias[n] : 0.0f;
    #pragma unroll
    for (int i = 0; i < 4; ++i) {
      #pragma unroll
      for (int r = 0; r < 4; ++r) {
        int m = mbase + wm + i * 16 + fq * 4 + r;
        float v = acc[i][j][r];
        if (flags & 4) v *= rowscale[m < NV ? m : (NV - 1)];
        v += bv;
        if (flags & 2) v = fmaxf(v, 0.0f);
        C[(size_t)m * Nreal + n] = f2bf(v);
      }
    }
  }
}

// GCN aggregate: out[n] = relu(dinv[n] * (hs[n] + sum_src hs[src]) + b), bf16 in/out
// processes 4 channels (one uint2 = 4 bf16) per thread; lc4 = log2(Cout/4)
__global__ void gcn_gather_kernel(const uint2* __restrict__ hs4,
                                  const float* __restrict__ bias,
                                  const float* __restrict__ dinv,
                                  const int* __restrict__ rowp, const int* __restrict__ esrc,
                                  uint2* __restrict__ out, int lc4) {
  int idx = blockIdx.x * blockDim.x + threadIdx.x;
  int C4 = 1 << lc4;
  if (idx >= NV * C4) return;
  int n = idx >> lc4;
  int j = idx & (C4 - 1);
  uint2 u = hs4[((size_t)n << lc4) + j];
  float a0 = bf2f(u.x & 0xffff), a1 = bf2f(u.x >> 16);
  float a2 = bf2f(u.y & 0xffff), a3 = bf2f(u.y >> 16);
  int s = rowp[n], e = rowp[n + 1];
  for (int t = s; t < e; ++t) {
    int src = esrc[t];
    uint2 v = hs4[((size_t)src << lc4) + j];
    a0 += bf2f(v.x & 0xffff); a1 += bf2f(v.x >> 16);
    a2 += bf2f(v.y & 0xffff); a3 += bf2f(v.y >> 16);
  }
  float dn = dinv[n];
  a0 = fmaxf(a0 * dn + bias[4 * j + 0], 0.0f);
  a1 = fmaxf(a1 * dn + bias[4 * j + 1], 0.0f);
  a2 = fmaxf(a2 * dn + bias[4 * j + 2], 0.0f);
  a3 = fmaxf(a3 * dn + bias[4 * j + 3], 0.0f);
  uint2 o;
  o.x = (unsigned int)f2bf(a0) | ((unsigned int)f2bf(a1) << 16);
  o.y = (unsigned int)f2bf(a2) | ((unsigned int)f2bf(a3) << 16);
  out[idx] = o;
}

// final head: out[n][k] = verts[n][k] + clip(tanh(d[n].hW3[:,k] + hb3[k]), -2.5, 2.5)
__global__ void head3_kernel(const unsigned short* __restrict__ d, const float* __restrict__ hW3,
                             const float* __restrict__ hb3, const float* __restrict__ verts,
                             float* __restrict__ out) {
  int idx = blockIdx.x * blockDim.x + threadIdx.x;
  if (idx >= NV * 3) return;
  int n = idx / 3;
  int k = idx - n * 3;
  float acc = hb3[k];
  #pragma unroll 8
  for (int c = 0; c < 64; ++c) acc += bf2f(d[n * 64 + c]) * hW3[c * 3 + k];
  float t = tanhf(acc);
  t = fminf(fmaxf(t, -2.5f), 2.5f);
  out[idx] = verts[idx] + t;
}

// ---------------- launch ----------------

static inline void launch_gemm(const unsigned short* A, const unsigned short* Bt,
                               const float* bias, const float* rowscale, unsigned short* C,
                               int N, int K, int flags, hipStream_t stream) {
  int Npad = (N + BN - 1) / BN * BN;
  dim3 grid(Npad / BN, NV_PAD / BM);
  gemm_bt_kernel<<<grid, 256, 0, stream>>>(A, Bt, bias, rowscale, C, K, N, flags);
}

extern "C" void kernel_launch(void* const* d_in, const int* in_sizes, int n_in,
                              void* d_out, int out_size, void* d_ws, size_t ws_size,
                              hipStream_t stream) {
  const float* features = (const float*)d_in[0];
  const float* vertices = (const float*)d_in[1];
  const int* edge_index = (const int*)d_in[2];
  const int E = in_sizes[2] / 2;
  const int* esrc_in = edge_index;       // edge_index[0] = src
  const int* edst_in = edge_index + E;   // edge_index[1] = dst
  const float* enc_W1 = (const float*)d_in[3];
  const float* enc_b1 = (const float*)d_in[4];
  const float* enc_W2 = (const float*)d_in[5];
  const float* enc_b2 = (const float*)d_in[6];
  const float* gW[6]; const float* gb[6];
  for (int i = 0; i < 6; ++i) { gW[i] = (const float*)d_in[7 + 2 * i]; gb[i] = (const float*)d_in[8 + 2 * i]; }
  const float* hW1 = (const float*)d_in[19]; const float* hb1 = (const float*)d_in[20];
  const float* hW2 = (const float*)d_in[21]; const float* hb2 = (const float*)d_in[22];
  const float* hW3 = (const float*)d_in[23]; const float* hb3 = (const float*)d_in[24];

  char* ws = (char*)d_ws;
  size_t off = 0;
  auto alloc = [&](size_t bytes) -> void* {
    void* p = (void*)(ws + off);
    off += (bytes + 255) & ~(size_t)255;
    return p;
  };
  unsigned short* bufA = (unsigned short*)alloc((size_t)NV_PAD * 1024 * 2);
  unsigned short* bufB = (unsigned short*)alloc((size_t)NV_PAD * 1024 * 2);
  float* dinv  = (float*)alloc(NV * sizeof(float));
  float* vfeat = (float*)alloc(NB * CF * sizeof(float));
  float* encc  = (float*)alloc(NB * 256 * sizeof(float));
  int* cnt  = (int*)alloc(NV * sizeof(int));
  int* rowp = (int*)alloc((NV + 1) * sizeof(int));
  int* cnt2 = (int*)alloc(NV * sizeof(int));
  int* esrc = (int*)alloc((size_t)E * sizeof(int));
  // bf16 transposed weights arena: rows padded to >=128
  const size_t wtsz[9] = {128 * 256, 256 * 128, 512 * 256, 1024 * 512, 512 * 1024,
                          256 * 512, 128 * 256, 128 * 128, 128 * 128};
  unsigned short* wt[9];
  size_t wt_total = 0;
  for (int i = 0; i < 9; ++i) wt_total += wtsz[i];
  unsigned short* wt_base = (unsigned short*)alloc(wt_total * 2);
  {
    size_t o = 0;
    for (int i = 0; i < 9; ++i) { wt[i] = wt_base + o; o += wtsz[i]; }
  }

  hipMemsetAsync(cnt,  0, NV * sizeof(int), stream);
  hipMemsetAsync(cnt2, 0, NV * sizeof(int), stream);
  hipMemsetAsync(wt_base, 0, wt_total * 2, stream);
  hist_dst_kernel<<<(E + 255) / 256, 256, 0, stream>>>(edst_in, E, cnt);
  scan_kernel<<<1, 1024, 0, stream>>>(cnt, rowp, dinv, NV);
  fill_csr_kernel<<<(E + 255) / 256, 256, 0, stream>>>(esrc_in, edst_in, E, rowp, cnt2, esrc);
  vfeat_kernel<<<1, 256, 0, stream>>>(features, vfeat);
  encconst_kernel<<<NB, 256, 0, stream>>>(vfeat, enc_W1, enc_b1, encc);

  // weight prep (transpose + bf16 cast)
  const float* wsrc[9] = {enc_W2, gW[0], gW[1], gW[2], gW[3], gW[4], gW[5], hW1, hW2};
  const int wK[9] = {256, 128, 256, 512, 1024, 512, 256, 128, 128};
  const int wN[9] = {128, 256, 512, 1024, 512, 256, 128, 128, 64};
  for (int i = 0; i < 9; ++i) {
    int cnt_el = wK[i] * wN[i];
    wprep_kernel<<<(cnt_el + 255) / 256, 256, 0, stream>>>(wsrc[i], wt[i], wK[i], wN[i]);
  }

  const int gout[6] = {256, 512, 1024, 512, 256, 128};
  const int gin[6]  = {128, 256, 512, 1024, 512, 256};
  const int glc4[6] = {6, 7, 8, 7, 6, 5};  // log2(Cout/4)

  for (int b = 0; b < NB; ++b) {
    // enc layer 1 -> bufA [NV,256] bf16
    enc1_kernel<<<(NV * 256 + 255) / 256, 256, 0, stream>>>(vertices, enc_W1, encc + b * 256, bufA);
    // enc layer 2 -> bufB [NV,128]
    launch_gemm(bufA, wt[0], enc_b2, nullptr, bufB, 128, 256, 1 | 2, stream);

    unsigned short* x = bufB;
    unsigned short* h = bufA;
    for (int i = 0; i < 6; ++i) {
      // hs = (x @ gW) * dinv[row]   (no bias/relu)
      launch_gemm(x, wt[1 + i], nullptr, dinv, h, gout[i], gin[i], 4, stream);
      int total4 = NV * (gout[i] / 4);
      gcn_gather_kernel<<<(total4 + 255) / 256, 256, 0, stream>>>(
          (const uint2*)h, gb[i], dinv, rowp, esrc, (uint2*)x, glc4[i]);
    }
    // head
    launch_gemm(x, wt[7], hb1, nullptr, h, 128, 128, 1 | 2, stream);  // bufA [NV,128]
    launch_gemm(h, wt[8], hb2, nullptr, x, 64, 128, 1 | 2, stream);   // bufB [NV,64]
    head3_kernel<<<(NV * 3 + 255) / 256, 256, 0, stream>>>(x, hW3, hb3, vertices,
                                                           (float*)d_out + (size_t)b * NV * 3);
  }
}

// Round 3
// 1488.892 us; speedup vs baseline: 3.7999x; 1.4624x over previous
//
#include <hip/hip_runtime.h>
#include <math.h>

#define NV 20000
#define NV_PAD 20096            // 157 * 128
#define NB 4
#define M_TOTAL (NB * NV_PAD)   // 80384 = 628 * 128
#define CF 64
#define VX 64

typedef short short8 __attribute__((ext_vector_type(8)));
typedef float floatx4 __attribute__((ext_vector_type(4)));

__device__ __forceinline__ float bf2f(unsigned int h) {
  return __uint_as_float(h << 16);
}
__device__ __forceinline__ unsigned short f2bf(float f) {
  unsigned int u = __float_as_uint(f);
  u += 0x7fffu + ((u >> 16) & 1u);   // round-to-nearest-even
  return (unsigned short)(u >> 16);
}

// ---------------- CSR construction (dst-sorted) ----------------

__global__ void hist_dst_kernel(const int* __restrict__ dst, int E, int* __restrict__ cnt) {
  int i = blockIdx.x * blockDim.x + threadIdx.x;
  if (i < E) atomicAdd(&cnt[dst[i]], 1);
}

__global__ void scan_kernel(const int* __restrict__ cnt, int* __restrict__ rowp,
                            float* __restrict__ dinv, int n) {
  __shared__ int sdata[1024];
  __shared__ int run_s;
  if (threadIdx.x == 0) run_s = 0;
  __syncthreads();
  for (int base = 0; base < n; base += 1024) {
    int i = base + (int)threadIdx.x;
    int v = (i < n) ? cnt[i] : 0;
    sdata[threadIdx.x] = v;
    __syncthreads();
    int run = run_s;
    for (int ofs = 1; ofs < 1024; ofs <<= 1) {
      int t = (threadIdx.x >= (unsigned)ofs) ? sdata[threadIdx.x - ofs] : 0;
      __syncthreads();
      sdata[threadIdx.x] += t;
      __syncthreads();
    }
    if (i < n) {
      rowp[i] = run + sdata[threadIdx.x] - v;
      dinv[i] = 1.0f / sqrtf((float)(v + 1));
    }
    if (threadIdx.x == 1023) run_s = run + sdata[1023];
    __syncthreads();
  }
  if (threadIdx.x == 0) rowp[n] = run_s;
}

__global__ void fill_csr_kernel(const int* __restrict__ src, const int* __restrict__ dst, int E,
                                const int* __restrict__ rowp, int* __restrict__ cnt2,
                                int* __restrict__ esrc) {
  int i = blockIdx.x * blockDim.x + threadIdx.x;
  if (i < E) {
    int d = dst[i];
    int pos = rowp[d] + atomicAdd(&cnt2[d], 1);
    esrc[pos] = src[i];
  }
}

// dinv replicated per batch with pad rows = 1.0
__global__ void dinvrep_kernel(const float* __restrict__ dinv, float* __restrict__ drep) {
  int idx = blockIdx.x * blockDim.x + threadIdx.x;
  if (idx >= M_TOTAL) return;
  int n = idx % NV_PAD;
  drep[idx] = (n < NV) ? dinv[n] : 1.0f;
}

// ---------------- constant feature sample ----------------
// vn == -1 exactly (batch-min of identical copies), /1.5 -> constant grid point.
__global__ void vfeat_kernel(const float* __restrict__ feat, float* __restrict__ vfeat) {
  int t = blockIdx.x * blockDim.x + threadIdx.x;
  if (t >= NB * CF) return;
  float c = (2.0f * 0.0f / 1e-6f - 1.0f) / 1.5f;
  float pos = (c + 1.0f) * 0.5f * (float)(VX - 1);
  pos = fminf(fmaxf(pos, 0.0f), (float)(VX - 1));
  float f0 = floorf(pos);
  float w = pos - f0;
  int i0 = (int)f0;
  int i1 = i0 + 1; if (i1 > VX - 1) i1 = VX - 1;
  const float* base = feat + (size_t)t * VX * VX * VX;
  float wz[2] = {1.0f - w, w};
  int   iz[2] = {i0, i1};
  float acc = 0.0f;
  #pragma unroll
  for (int a = 0; a < 2; ++a)
    #pragma unroll
    for (int b = 0; b < 2; ++b)
      #pragma unroll
      for (int d = 0; d < 2; ++d)
        acc += wz[a] * wz[b] * wz[d] * base[(size_t)iz[a] * VX * VX + iz[b] * VX + iz[d]];
  vfeat[t] = acc;
}

__global__ void encconst_kernel(const float* __restrict__ vfeat, const float* __restrict__ W1,
                                const float* __restrict__ b1, float* __restrict__ encc) {
  int idx = blockIdx.x * blockDim.x + threadIdx.x;
  if (idx >= NB * 256) return;
  int b = idx >> 8, j = idx & 255;
  float acc = b1[j];
  #pragma unroll 8
  for (int c = 0; c < CF; ++c) acc += vfeat[b * CF + c] * W1[(3 + c) * 256 + j];
  encc[idx] = acc;
}

// x1[row][j] = relu(v[n].W1[0:3][j] + encc[b][j]) -> bf16 ; batched via blockIdx.y
__global__ void enc1_kernel(const float* __restrict__ verts, const float* __restrict__ W1,
                            const float* __restrict__ encc, unsigned short* __restrict__ out) {
  int idx = blockIdx.x * blockDim.x + threadIdx.x;
  if (idx >= NV * 256) return;
  int n = idx >> 8, j = idx & 255;
  int b = blockIdx.y;
  float acc = encc[b * 256 + j]
            + verts[n * 3 + 0] * W1[0 * 256 + j]
            + verts[n * 3 + 1] * W1[1 * 256 + j]
            + verts[n * 3 + 2] * W1[2 * 256 + j];
  out[((size_t)(b * NV_PAD + n)) * 256 + j] = f2bf(fmaxf(acc, 0.0f));
}

// ---------------- combined weight prep (fp32 [K,N] -> bf16 transposed [N,K]) ----------------
struct WPrep {
  const float* src[9];
  unsigned short* dst[9];
};

__global__ void wprep_all_kernel(WPrep wp) {
  const int WKc[9] = {256, 128, 256, 512, 1024, 512, 256, 128, 128};
  const int WNc[9] = {128, 256, 512, 1024, 512, 256, 128, 128, 64};
  const int cum[10] = {0, 32768, 65536, 196608, 720896, 1245184, 1376256, 1409024, 1425408, 1433600};
  int idx = blockIdx.x * blockDim.x + threadIdx.x;
  if (idx >= 1433600) return;
  #pragma unroll
  for (int s = 0; s < 9; ++s) {
    if (idx >= cum[s] && idx < cum[s + 1]) {
      int local = idx - cum[s];
      int k = local / WNc[s];
      int n = local - k * WNc[s];
      wp.dst[s][(size_t)n * WKc[s] + k] = f2bf(wp.src[s][local]);
      return;
    }
  }
}

// ---------------- bf16 MFMA GEMM (m97-style gemm_bt) ----------------
// C[M_TOTAL,N] = A[M_TOTAL,K] @ Bt[N,K]^T ; 128x128 tile, BK=32, 4 waves.
// flags: 1=bias, 2=relu, 4=rowscale[m]
#define BM 128
#define BN 128
#define BK 32

__launch_bounds__(256, 2)
__global__ void gemm_bt_kernel(const unsigned short* __restrict__ A,
                               const unsigned short* __restrict__ Bt,
                               const float* __restrict__ bias,
                               const float* __restrict__ rowscale,
                               unsigned short* __restrict__ C,
                               int K, int Nreal, int flags) {
  __shared__ unsigned short As[BM * BK];  // [m][k], row = 32 elems = 64 B
  __shared__ unsigned short Bs[BN * BK];  // [n][k]
  int tid = threadIdx.x;
  int wave = tid >> 6, lane = tid & 63;
  int mbase = blockIdx.y * BM;
  int nbase = blockIdx.x * BN;
  int wm = (wave >> 1) * 64, wn = (wave & 1) * 64;

  floatx4 acc[4][4] = {};

  const int rowS = wave * 16 + (lane >> 2);   // staging row (+ p*64)
  const int kseg = (lane & 3) * 8;            // staging k offset (elements)
  const int fr = lane & 15, fq = lane >> 4;   // fragment row / quad

  for (int kb = 0; kb < K; kb += BK) {
    #pragma unroll
    for (int p = 0; p < 2; ++p) {
      const unsigned short* ga = A + (size_t)(mbase + rowS + p * 64) * K + kb + kseg;
      __builtin_amdgcn_global_load_lds(
          (const __attribute__((address_space(1))) void*)ga,
          (__attribute__((address_space(3))) void*)(As + wave * 512 + p * 2048), 16, 0, 0);
      const unsigned short* gb = Bt + (size_t)(nbase + rowS + p * 64) * K + kb + kseg;
      __builtin_amdgcn_global_load_lds(
          (const __attribute__((address_space(1))) void*)gb,
          (__attribute__((address_space(3))) void*)(Bs + wave * 512 + p * 2048), 16, 0, 0);
    }
    __syncthreads();
    short8 af[4], bf[4];
    #pragma unroll
    for (int i = 0; i < 4; ++i)
      af[i] = *(const short8*)(As + (wm + i * 16 + fr) * BK + fq * 8);
    #pragma unroll
    for (int j = 0; j < 4; ++j)
      bf[j] = *(const short8*)(Bs + (wn + j * 16 + fr) * BK + fq * 8);
    #pragma unroll
    for (int i = 0; i < 4; ++i)
      #pragma unroll
      for (int j = 0; j < 4; ++j)
        acc[i][j] = __builtin_amdgcn_mfma_f32_16x16x32_bf16(af[i], bf[j], acc[i][j], 0, 0, 0);
    __syncthreads();
  }

  // epilogue: C/D layout col = lane&15, row = (lane>>4)*4 + r
  #pragma unroll
  for (int j = 0; j < 4; ++j) {
    int n = nbase + wn + j * 16 + fr;
    if (n >= Nreal) continue;
    float bv = (flags & 1) ? bias[n] : 0.0f;
    #pragma unroll
    for (int i = 0; i < 4; ++i) {
      #pragma unroll
      for (int r = 0; r < 4; ++r) {
        int m = mbase + wm + i * 16 + fq * 4 + r;
        float v = acc[i][j][r];
        if (flags & 4) v *= rowscale[m];
        v += bv;
        if (flags & 2) v = fmaxf(v, 0.0f);
        C[(size_t)m * Nreal + n] = f2bf(v);
      }
    }
  }
}

// GCN aggregate: out[n] = relu(dinv[n] * (hs[n] + sum_src hs[src]) + b), bf16 in/out.
// 8 channels (uint4) per thread; batched via blockIdx.y; lc8 = log2(Cout/8).
__global__ void gcn_gather_kernel(const uint4* __restrict__ hs8,
                                  const float* __restrict__ bias,
                                  const float* __restrict__ dinv,
                                  const int* __restrict__ rowp, const int* __restrict__ esrc,
                                  uint4* __restrict__ out, int lc8) {
  int idx = blockIdx.x * blockDim.x + threadIdx.x;
  int C8 = 1 << lc8;
  if (idx >= NV * C8) return;
  int n = idx >> lc8;
  int j = idx & (C8 - 1);
  size_t rowbase = (size_t)blockIdx.y * NV_PAD;
  uint4 u = hs8[((rowbase + n) << lc8) + j];
  float a0 = bf2f(u.x & 0xffff), a1 = bf2f(u.x >> 16);
  float a2 = bf2f(u.y & 0xffff), a3 = bf2f(u.y >> 16);
  float a4 = bf2f(u.z & 0xffff), a5 = bf2f(u.z >> 16);
  float a6 = bf2f(u.w & 0xffff), a7 = bf2f(u.w >> 16);
  int s = rowp[n], e = rowp[n + 1];
  for (int t = s; t < e; ++t) {
    int src = esrc[t];
    uint4 v = hs8[((rowbase + src) << lc8) + j];
    a0 += bf2f(v.x & 0xffff); a1 += bf2f(v.x >> 16);
    a2 += bf2f(v.y & 0xffff); a3 += bf2f(v.y >> 16);
    a4 += bf2f(v.z & 0xffff); a5 += bf2f(v.z >> 16);
    a6 += bf2f(v.w & 0xffff); a7 += bf2f(v.w >> 16);
  }
  float dn = dinv[n];
  int j8 = j << 3;
  a0 = fmaxf(a0 * dn + bias[j8 + 0], 0.0f);
  a1 = fmaxf(a1 * dn + bias[j8 + 1], 0.0f);
  a2 = fmaxf(a2 * dn + bias[j8 + 2], 0.0f);
  a3 = fmaxf(a3 * dn + bias[j8 + 3], 0.0f);
  a4 = fmaxf(a4 * dn + bias[j8 + 4], 0.0f);
  a5 = fmaxf(a5 * dn + bias[j8 + 5], 0.0f);
  a6 = fmaxf(a6 * dn + bias[j8 + 6], 0.0f);
  a7 = fmaxf(a7 * dn + bias[j8 + 7], 0.0f);
  uint4 o;
  o.x = (unsigned int)f2bf(a0) | ((unsigned int)f2bf(a1) << 16);
  o.y = (unsigned int)f2bf(a2) | ((unsigned int)f2bf(a3) << 16);
  o.z = (unsigned int)f2bf(a4) | ((unsigned int)f2bf(a5) << 16);
  o.w = (unsigned int)f2bf(a6) | ((unsigned int)f2bf(a7) << 16);
  out[((rowbase + n) << lc8) + j] = o;
}

// final head, batched via blockIdx.y
__global__ void head3_kernel(const unsigned short* __restrict__ d, const float* __restrict__ hW3,
                             const float* __restrict__ hb3, const float* __restrict__ verts,
                             float* __restrict__ out) {
  int idx = blockIdx.x * blockDim.x + threadIdx.x;
  if (idx >= NV * 3) return;
  int n = idx / 3;
  int k = idx - n * 3;
  int b = blockIdx.y;
  const unsigned short* drow = d + ((size_t)(b * NV_PAD + n)) * 64;
  float acc = hb3[k];
  #pragma unroll 8
  for (int c = 0; c < 64; ++c) acc += bf2f(drow[c]) * hW3[c * 3 + k];
  float t = tanhf(acc);
  t = fminf(fmaxf(t, -2.5f), 2.5f);
  out[(size_t)b * NV * 3 + idx] = verts[idx] + t;
}

// ---------------- launch ----------------

static inline void launch_gemm(const unsigned short* A, const unsigned short* Bt,
                               const float* bias, const float* rowscale, unsigned short* C,
                               int N, int K, int flags, hipStream_t stream) {
  int Npad = (N + BN - 1) / BN * BN;
  dim3 grid(Npad / BN, M_TOTAL / BM);
  gemm_bt_kernel<<<grid, 256, 0, stream>>>(A, Bt, bias, rowscale, C, K, N, flags);
}

extern "C" void kernel_launch(void* const* d_in, const int* in_sizes, int n_in,
                              void* d_out, int out_size, void* d_ws, size_t ws_size,
                              hipStream_t stream) {
  const float* features = (const float*)d_in[0];
  const float* vertices = (const float*)d_in[1];
  const int* edge_index = (const int*)d_in[2];
  const int E = in_sizes[2] / 2;
  const int* esrc_in = edge_index;       // edge_index[0] = src
  const int* edst_in = edge_index + E;   // edge_index[1] = dst
  const float* enc_W1 = (const float*)d_in[3];
  const float* enc_b1 = (const float*)d_in[4];
  const float* enc_W2 = (const float*)d_in[5];
  const float* enc_b2 = (const float*)d_in[6];
  const float* gW[6]; const float* gb[6];
  for (int i = 0; i < 6; ++i) { gW[i] = (const float*)d_in[7 + 2 * i]; gb[i] = (const float*)d_in[8 + 2 * i]; }
  const float* hW1 = (const float*)d_in[19]; const float* hb1 = (const float*)d_in[20];
  const float* hW2 = (const float*)d_in[21]; const float* hb2 = (const float*)d_in[22];
  const float* hW3 = (const float*)d_in[23]; const float* hb3 = (const float*)d_in[24];

  char* ws = (char*)d_ws;
  size_t off = 0;
  auto alloc = [&](size_t bytes) -> void* {
    void* p = (void*)(ws + off);
    off += (bytes + 255) & ~(size_t)255;
    return p;
  };
  unsigned short* bufA = (unsigned short*)alloc((size_t)M_TOTAL * 1024 * 2);
  unsigned short* bufB = (unsigned short*)alloc((size_t)M_TOTAL * 1024 * 2);
  float* dinv  = (float*)alloc(NV * sizeof(float));
  float* drep  = (float*)alloc(M_TOTAL * sizeof(float));
  float* vfeat = (float*)alloc(NB * CF * sizeof(float));
  float* encc  = (float*)alloc(NB * 256 * sizeof(float));
  int* cnt  = (int*)alloc(NV * sizeof(int));
  int* rowp = (int*)alloc((NV + 1) * sizeof(int));
  int* cnt2 = (int*)alloc(NV * sizeof(int));
  int* esrc = (int*)alloc((size_t)E * sizeof(int));
  // bf16 transposed weights (rows padded to >=128)
  const size_t wtsz[9] = {128 * 256, 256 * 128, 512 * 256, 1024 * 512, 512 * 1024,
                          256 * 512, 128 * 256, 128 * 128, 128 * 128};
  unsigned short* wt[9];
  {
    size_t tot = 0;
    for (int i = 0; i < 9; ++i) tot += wtsz[i];
    unsigned short* base = (unsigned short*)alloc(tot * 2);
    size_t o = 0;
    for (int i = 0; i < 9; ++i) { wt[i] = base + o; o += wtsz[i]; }
  }

  hipMemsetAsync(cnt,  0, NV * sizeof(int), stream);
  hipMemsetAsync(cnt2, 0, NV * sizeof(int), stream);
  hist_dst_kernel<<<(E + 255) / 256, 256, 0, stream>>>(edst_in, E, cnt);
  scan_kernel<<<1, 1024, 0, stream>>>(cnt, rowp, dinv, NV);
  fill_csr_kernel<<<(E + 255) / 256, 256, 0, stream>>>(esrc_in, edst_in, E, rowp, cnt2, esrc);
  dinvrep_kernel<<<(M_TOTAL + 255) / 256, 256, 0, stream>>>(dinv, drep);
  vfeat_kernel<<<1, 256, 0, stream>>>(features, vfeat);
  encconst_kernel<<<NB, 256, 0, stream>>>(vfeat, enc_W1, enc_b1, encc);

  WPrep wp;
  const float* wsrc[9] = {enc_W2, gW[0], gW[1], gW[2], gW[3], gW[4], gW[5], hW1, hW2};
  for (int i = 0; i < 9; ++i) { wp.src[i] = wsrc[i]; wp.dst[i] = wt[i]; }
  wprep_all_kernel<<<(1433600 + 255) / 256, 256, 0, stream>>>(wp);

  const int gout[6] = {256, 512, 1024, 512, 256, 128};
  const int gin[6]  = {128, 256, 512, 1024, 512, 256};
  const int glc8[6] = {5, 6, 7, 6, 5, 4};  // log2(Cout/8)

  // enc layer 1 (all batches) -> bufA [M_TOTAL,256]
  dim3 e1grid((NV * 256 + 255) / 256, NB);
  enc1_kernel<<<e1grid, 256, 0, stream>>>(vertices, enc_W1, encc, bufA);
  // enc layer 2 -> bufB [M_TOTAL,128]
  launch_gemm(bufA, wt[0], enc_b2, nullptr, bufB, 128, 256, 1 | 2, stream);

  unsigned short* x = bufB;
  unsigned short* h = bufA;
  for (int i = 0; i < 6; ++i) {
    // hs = (x @ gW) * dinv[row]   (no bias/relu)
    launch_gemm(x, wt[1 + i], nullptr, drep, h, gout[i], gin[i], 4, stream);
    int total8 = NV * (gout[i] / 8);
    dim3 ggrid((total8 + 255) / 256, NB);
    gcn_gather_kernel<<<ggrid, 256, 0, stream>>>(
        (const uint4*)h, gb[i], dinv, rowp, esrc, (uint4*)x, glc8[i]);
  }
  // head
  launch_gemm(x, wt[7], hb1, nullptr, h, 128, 128, 1 | 2, stream);  // bufA [M_TOTAL,128]
  launch_gemm(h, wt[8], hb2, nullptr, x, 64, 128, 1 | 2, stream);   // bufB [M_TOTAL,64]
  dim3 hgrid((NV * 3 + 255) / 256, NB);
  head3_kernel<<<hgrid, 256, 0, stream>>>(x, hW3, hb3, vertices, (float*)d_out);
}

// Round 5
// 1449.545 us; speedup vs baseline: 3.9030x; 1.0271x over previous
//
#include <hip/hip_runtime.h>
#include <math.h>

#define NV 20000
#define NV_PAD 20096            // 157 * 128
#define NB 4
#define M_TOTAL (NB * NV_PAD)   // 80384 = 628 * 128
#define CF 64
#define VX 64

typedef short short8 __attribute__((ext_vector_type(8)));
typedef float floatx4 __attribute__((ext_vector_type(4)));

__device__ __forceinline__ float bf2f(unsigned int h) {
  return __uint_as_float(h << 16);
}
__device__ __forceinline__ unsigned short f2bf(float f) {
  unsigned int u = __float_as_uint(f);
  u += 0x7fffu + ((u >> 16) & 1u);   // round-to-nearest-even
  return (unsigned short)(u >> 16);
}

// ---------------- CSR construction (dst-sorted) ----------------

__global__ void hist_dst_kernel(const int* __restrict__ dst, int E, int* __restrict__ cnt) {
  int i = blockIdx.x * blockDim.x + threadIdx.x;
  if (i < E) atomicAdd(&cnt[dst[i]], 1);
}

__global__ void scan_kernel(const int* __restrict__ cnt, int* __restrict__ rowp,
                            float* __restrict__ dinv, int n) {
  __shared__ int sdata[1024];
  __shared__ int run_s;
  if (threadIdx.x == 0) run_s = 0;
  __syncthreads();
  for (int base = 0; base < n; base += 1024) {
    int i = base + (int)threadIdx.x;
    int v = (i < n) ? cnt[i] : 0;
    sdata[threadIdx.x] = v;
    __syncthreads();
    int run = run_s;
    for (int ofs = 1; ofs < 1024; ofs <<= 1) {
      int t = (threadIdx.x >= (unsigned)ofs) ? sdata[threadIdx.x - ofs] : 0;
      __syncthreads();
      sdata[threadIdx.x] += t;
      __syncthreads();
    }
    if (i < n) {
      rowp[i] = run + sdata[threadIdx.x] - v;
      dinv[i] = 1.0f / sqrtf((float)(v + 1));
    }
    if (threadIdx.x == 1023) run_s = run + sdata[1023];
    __syncthreads();
  }
  if (threadIdx.x == 0) rowp[n] = run_s;
}

__global__ void fill_csr_kernel(const int* __restrict__ src, const int* __restrict__ dst, int E,
                                const int* __restrict__ rowp, int* __restrict__ cnt2,
                                int* __restrict__ esrc) {
  int i = blockIdx.x * blockDim.x + threadIdx.x;
  if (i < E) {
    int d = dst[i];
    int pos = rowp[d] + atomicAdd(&cnt2[d], 1);
    esrc[pos] = src[i];
  }
}

// dinv replicated per batch with pad rows = 1.0
__global__ void dinvrep_kernel(const float* __restrict__ dinv, float* __restrict__ drep) {
  int idx = blockIdx.x * blockDim.x + threadIdx.x;
  if (idx >= M_TOTAL) return;
  int n = idx % NV_PAD;
  drep[idx] = (n < NV) ? dinv[n] : 1.0f;
}

// ---------------- constant feature sample ----------------
// vn == -1 exactly (batch-min of identical copies), /1.5 -> constant grid point.
__global__ void vfeat_kernel(const float* __restrict__ feat, float* __restrict__ vfeat) {
  int t = blockIdx.x * blockDim.x + threadIdx.x;
  if (t >= NB * CF) return;
  float c = (2.0f * 0.0f / 1e-6f - 1.0f) / 1.5f;
  float pos = (c + 1.0f) * 0.5f * (float)(VX - 1);
  pos = fminf(fmaxf(pos, 0.0f), (float)(VX - 1));
  float f0 = floorf(pos);
  float w = pos - f0;
  int i0 = (int)f0;
  int i1 = i0 + 1; if (i1 > VX - 1) i1 = VX - 1;
  const float* base = feat + (size_t)t * VX * VX * VX;
  float wz[2] = {1.0f - w, w};
  int   iz[2] = {i0, i1};
  float acc = 0.0f;
  #pragma unroll
  for (int a = 0; a < 2; ++a)
    #pragma unroll
    for (int b = 0; b < 2; ++b)
      #pragma unroll
      for (int d = 0; d < 2; ++d)
        acc += wz[a] * wz[b] * wz[d] * base[(size_t)iz[a] * VX * VX + iz[b] * VX + iz[d]];
  vfeat[t] = acc;
}

__global__ void encconst_kernel(const float* __restrict__ vfeat, const float* __restrict__ W1,
                                const float* __restrict__ b1, float* __restrict__ encc) {
  int idx = blockIdx.x * blockDim.x + threadIdx.x;
  if (idx >= NB * 256) return;
  int b = idx >> 8, j = idx & 255;
  float acc = b1[j];
  #pragma unroll 8
  for (int c = 0; c < CF; ++c) acc += vfeat[b * CF + c] * W1[(3 + c) * 256 + j];
  encc[idx] = acc;
}

// x1[row][j] = relu(v[n].W1[0:3][j] + encc[b][j]) -> bf16 ; batched via blockIdx.y
__global__ void enc1_kernel(const float* __restrict__ verts, const float* __restrict__ W1,
                            const float* __restrict__ encc, unsigned short* __restrict__ out) {
  int idx = blockIdx.x * blockDim.x + threadIdx.x;
  if (idx >= NV * 256) return;
  int n = idx >> 8, j = idx & 255;
  int b = blockIdx.y;
  float acc = encc[b * 256 + j]
            + verts[n * 3 + 0] * W1[0 * 256 + j]
            + verts[n * 3 + 1] * W1[1 * 256 + j]
            + verts[n * 3 + 2] * W1[2 * 256 + j];
  out[((size_t)(b * NV_PAD + n)) * 256 + j] = f2bf(fmaxf(acc, 0.0f));
}

// ---------------- combined weight prep (fp32 [K,N] -> bf16 transposed [N,K]) ----------------
struct WPrep {
  const float* src[9];
  unsigned short* dst[9];
};

__global__ void wprep_all_kernel(WPrep wp) {
  const int WKc[9] = {256, 128, 256, 512, 1024, 512, 256, 128, 128};
  const int WNc[9] = {128, 256, 512, 1024, 512, 256, 128, 128, 64};
  const int cum[10] = {0, 32768, 65536, 196608, 720896, 1245184, 1376256, 1409024, 1425408, 1433600};
  int idx = blockIdx.x * blockDim.x + threadIdx.x;
  if (idx >= 1433600) return;
  #pragma unroll
  for (int s = 0; s < 9; ++s) {
    if (idx >= cum[s] && idx < cum[s + 1]) {
      int local = idx - cum[s];
      int k = local / WNc[s];
      int n = local - k * WNc[s];
      wp.dst[s][(size_t)n * WKc[s] + k] = f2bf(wp.src[s][local]);
      return;
    }
  }
}

// ---------------- bf16 MFMA GEMM (m97-style gemm_bt, XOR-swizzled LDS) ----------------
// C[M_TOTAL,N] = A[M_TOTAL,K] @ Bt[N,K]^T ; 128x128 tile, BK=32, 4 waves.
// LDS chunk swizzle: slot (row, c) holds global k-chunk (c ^ swz(row)), swz(r)=(r+(r>>2))&3.
// swz has period 16 in row, so staging uses swz(lane>>2) and fragments swz(fr).
// flags: 1=bias, 2=relu, 4=rowscale[m]
#define BM 128
#define BN 128
#define BK 32

__launch_bounds__(256, 4)
__global__ void gemm_bt_kernel(const unsigned short* __restrict__ A,
                               const unsigned short* __restrict__ Bt,
                               const float* __restrict__ bias,
                               const float* __restrict__ rowscale,
                               unsigned short* __restrict__ C,
                               int K, int Nreal, int flags) {
  __shared__ unsigned short As[BM * BK];  // [m][k], row = 32 elems = 64 B
  __shared__ unsigned short Bs[BN * BK];  // [n][k]
  int tid = threadIdx.x;
  int wave = tid >> 6, lane = tid & 63;
  int mbase = blockIdx.y * BM;
  int nbase = blockIdx.x * BN;
  int wm = (wave >> 1) * 64, wn = (wave & 1) * 64;

  floatx4 acc[4][4] = {};

  const int rowS = wave * 16 + (lane >> 2);                 // staging row (+ p*64)
  const int sswz = ((lane >> 2) + (lane >> 4)) & 3;         // swz(lane>>2)
  const int kseg = (((lane & 3) ^ sswz) << 3);              // swizzled global chunk (elems)
  const int fr = lane & 15, fq = lane >> 4;                 // fragment row / quad
  const int fswz = (fr + (fr >> 2)) & 3;                    // swz(fr)
  const int fchunk = ((fq ^ fswz) << 3);                    // LDS chunk for fragment reads

  for (int kb = 0; kb < K; kb += BK) {
    #pragma unroll
    for (int p = 0; p < 2; ++p) {
      const unsigned short* ga = A + (size_t)(mbase + rowS + p * 64) * K + kb + kseg;
      __builtin_amdgcn_global_load_lds(
          (const __attribute__((address_space(1))) void*)ga,
          (__attribute__((address_space(3))) void*)(As + wave * 512 + p * 2048), 16, 0, 0);
      const unsigned short* gb = Bt + (size_t)(nbase + rowS + p * 64) * K + kb + kseg;
      __builtin_amdgcn_global_load_lds(
          (const __attribute__((address_space(1))) void*)gb,
          (__attribute__((address_space(3))) void*)(Bs + wave * 512 + p * 2048), 16, 0, 0);
    }
    __syncthreads();
    short8 af[4], bf[4];
    #pragma unroll
    for (int i = 0; i < 4; ++i)
      af[i] = *(const short8*)(As + (wm + i * 16 + fr) * BK + fchunk);
    #pragma unroll
    for (int j = 0; j < 4; ++j)
      bf[j] = *(const short8*)(Bs + (wn + j * 16 + fr) * BK + fchunk);
    #pragma unroll
    for (int i = 0; i < 4; ++i)
      #pragma unroll
      for (int j = 0; j < 4; ++j)
        acc[i][j] = __builtin_amdgcn_mfma_f32_16x16x32_bf16(af[i], bf[j], acc[i][j], 0, 0, 0);
    __syncthreads();
  }

  // epilogue: C/D layout col = lane&15, row = (lane>>4)*4 + r
  #pragma unroll
  for (int j = 0; j < 4; ++j) {
    int n = nbase + wn + j * 16 + fr;
    if (n >= Nreal) continue;
    float bv = (flags & 1) ? bias[n] : 0.0f;
    #pragma unroll
    for (int i = 0; i < 4; ++i) {
      #pragma unroll
      for (int r = 0; r < 4; ++r) {
        int m = mbase + wm + i * 16 + fq * 4 + r;
        float v = acc[i][j][r];
        if (flags & 4) v *= rowscale[m];
        v += bv;
        if (flags & 2) v = fmaxf(v, 0.0f);
        C[(size_t)m * Nreal + n] = f2bf(v);
      }
    }
  }
}

// GCN aggregate: out[n] = relu(dinv[n] * (hs[n] + sum_src hs[src]) + b), bf16 in/out.
// 8 channels (uint4) per thread; batched via blockIdx.y; lc8 = log2(Cout/8).
__global__ void gcn_gather_kernel(const uint4* __restrict__ hs8,
                                  const float* __restrict__ bias,
                                  const float* __restrict__ dinv,
                                  const int* __restrict__ rowp, const int* __restrict__ esrc,
                                  uint4* __restrict__ out, int lc8) {
  int idx = blockIdx.x * blockDim.x + threadIdx.x;
  int C8 = 1 << lc8;
  if (idx >= NV * C8) return;
  int n = idx >> lc8;
  int j = idx & (C8 - 1);
  size_t rowbase = (size_t)blockIdx.y * NV_PAD;
  uint4 u = hs8[((rowbase + n) << lc8) + j];
  float a0 = bf2f(u.x & 0xffff), a1 = bf2f(u.x >> 16);
  float a2 = bf2f(u.y & 0xffff), a3 = bf2f(u.y >> 16);
  float a4 = bf2f(u.z & 0xffff), a5 = bf2f(u.z >> 16);
  float a6 = bf2f(u.w & 0xffff), a7 = bf2f(u.w >> 16);
  int s = rowp[n], e = rowp[n + 1];
  int t = s;
  int src = (t < e) ? esrc[t] : 0;
  while (t < e) {
    uint4 v = hs8[((rowbase + src) << lc8) + j];
    ++t;
    int src_n = (t < e) ? esrc[t] : 0;
    a0 += bf2f(v.x & 0xffff); a1 += bf2f(v.x >> 16);
    a2 += bf2f(v.y & 0xffff); a3 += bf2f(v.y >> 16);
    a4 += bf2f(v.z & 0xffff); a5 += bf2f(v.z >> 16);
    a6 += bf2f(v.w & 0xffff); a7 += bf2f(v.w >> 16);
    src = src_n;
  }
  float dn = dinv[n];
  int j8 = j << 3;
  a0 = fmaxf(a0 * dn + bias[j8 + 0], 0.0f);
  a1 = fmaxf(a1 * dn + bias[j8 + 1], 0.0f);
  a2 = fmaxf(a2 * dn + bias[j8 + 2], 0.0f);
  a3 = fmaxf(a3 * dn + bias[j8 + 3], 0.0f);
  a4 = fmaxf(a4 * dn + bias[j8 + 4], 0.0f);
  a5 = fmaxf(a5 * dn + bias[j8 + 5], 0.0f);
  a6 = fmaxf(a6 * dn + bias[j8 + 6], 0.0f);
  a7 = fmaxf(a7 * dn + bias[j8 + 7], 0.0f);
  uint4 o;
  o.x = (unsigned int)f2bf(a0) | ((unsigned int)f2bf(a1) << 16);
  o.y = (unsigned int)f2bf(a2) | ((unsigned int)f2bf(a3) << 16);
  o.z = (unsigned int)f2bf(a4) | ((unsigned int)f2bf(a5) << 16);
  o.w = (unsigned int)f2bf(a6) | ((unsigned int)f2bf(a7) << 16);
  out[((rowbase + n) << lc8) + j] = o;
}

// final head, batched via blockIdx.y
__global__ void head3_kernel(const unsigned short* __restrict__ d, const float* __restrict__ hW3,
                             const float* __restrict__ hb3, const float* __restrict__ verts,
                             float* __restrict__ out) {
  int idx = blockIdx.x * blockDim.x + threadIdx.x;
  if (idx >= NV * 3) return;
  int n = idx / 3;
  int k = idx - n * 3;
  int b = blockIdx.y;
  const unsigned short* drow = d + ((size_t)(b * NV_PAD + n)) * 64;
  float acc = hb3[k];
  #pragma unroll 8
  for (int c = 0; c < 64; ++c) acc += bf2f(drow[c]) * hW3[c * 3 + k];
  float t = tanhf(acc);
  t = fminf(fmaxf(t, -2.5f), 2.5f);
  out[(size_t)b * NV * 3 + idx] = verts[idx] + t;
}

// ---------------- launch ----------------

static inline void launch_gemm(const unsigned short* A, const unsigned short* Bt,
                               const float* bias, const float* rowscale, unsigned short* C,
                               int N, int K, int flags, hipStream_t stream) {
  int Npad = (N + BN - 1) / BN * BN;
  dim3 grid(Npad / BN, M_TOTAL / BM);
  gemm_bt_kernel<<<grid, 256, 0, stream>>>(A, Bt, bias, rowscale, C, K, N, flags);
}

extern "C" void kernel_launch(void* const* d_in, const int* in_sizes, int n_in,
                              void* d_out, int out_size, void* d_ws, size_t ws_size,
                              hipStream_t stream) {
  const float* features = (const float*)d_in[0];
  const float* vertices = (const float*)d_in[1];
  const int* edge_index = (const int*)d_in[2];
  const int E = in_sizes[2] / 2;
  const int* esrc_in = edge_index;       // edge_index[0] = src
  const int* edst_in = edge_index + E;   // edge_index[1] = dst
  const float* enc_W1 = (const float*)d_in[3];
  const float* enc_b1 = (const float*)d_in[4];
  const float* enc_W2 = (const float*)d_in[5];
  const float* enc_b2 = (const float*)d_in[6];
  const float* gW[6]; const float* gb[6];
  for (int i = 0; i < 6; ++i) { gW[i] = (const float*)d_in[7 + 2 * i]; gb[i] = (const float*)d_in[8 + 2 * i]; }
  const float* hW1 = (const float*)d_in[19]; const float* hb1 = (const float*)d_in[20];
  const float* hW2 = (const float*)d_in[21]; const float* hb2 = (const float*)d_in[22];
  const float* hW3 = (const float*)d_in[23]; const float* hb3 = (const float*)d_in[24];

  char* ws = (char*)d_ws;
  size_t off = 0;
  auto alloc = [&](size_t bytes) -> void* {
    void* p = (void*)(ws + off);
    off += (bytes + 255) & ~(size_t)255;
    return p;
  };
  unsigned short* bufA = (unsigned short*)alloc((size_t)M_TOTAL * 1024 * 2);
  unsigned short* bufB = (unsigned short*)alloc((size_t)M_TOTAL * 1024 * 2);
  float* dinv  = (float*)alloc(NV * sizeof(float));
  float* drep  = (float*)alloc(M_TOTAL * sizeof(float));
  float* vfeat = (float*)alloc(NB * CF * sizeof(float));
  float* encc  = (float*)alloc(NB * 256 * sizeof(float));
  int* cnt  = (int*)alloc(NV * sizeof(int));
  int* rowp = (int*)alloc((NV + 1) * sizeof(int));
  int* cnt2 = (int*)alloc(NV * sizeof(int));
  int* esrc = (int*)alloc((size_t)E * sizeof(int));
  // bf16 transposed weights (rows padded to >=128)
  const size_t wtsz[9] = {128 * 256, 256 * 128, 512 * 256, 1024 * 512, 512 * 1024,
                          256 * 512, 128 * 256, 128 * 128, 128 * 128};
  unsigned short* wt[9];
  {
    size_t tot = 0;
    for (int i = 0; i < 9; ++i) tot += wtsz[i];
    unsigned short* base = (unsigned short*)alloc(tot * 2);
    size_t o = 0;
    for (int i = 0; i < 9; ++i) { wt[i] = base + o; o += wtsz[i]; }
  }

  hipMemsetAsync(cnt,  0, NV * sizeof(int), stream);
  hipMemsetAsync(cnt2, 0, NV * sizeof(int), stream);
  hist_dst_kernel<<<(E + 255) / 256, 256, 0, stream>>>(edst_in, E, cnt);
  scan_kernel<<<1, 1024, 0, stream>>>(cnt, rowp, dinv, NV);
  fill_csr_kernel<<<(E + 255) / 256, 256, 0, stream>>>(esrc_in, edst_in, E, rowp, cnt2, esrc);
  dinvrep_kernel<<<(M_TOTAL + 255) / 256, 256, 0, stream>>>(dinv, drep);
  vfeat_kernel<<<1, 256, 0, stream>>>(features, vfeat);
  encconst_kernel<<<NB, 256, 0, stream>>>(vfeat, enc_W1, enc_b1, encc);

  WPrep wp;
  const float* wsrc[9] = {enc_W2, gW[0], gW[1], gW[2], gW[3], gW[4], gW[5], hW1, hW2};
  for (int i = 0; i < 9; ++i) { wp.src[i] = wsrc[i]; wp.dst[i] = wt[i]; }
  wprep_all_kernel<<<(1433600 + 255) / 256, 256, 0, stream>>>(wp);

  const int gout[6] = {256, 512, 1024, 512, 256, 128};
  const int gin[6]  = {128, 256, 512, 1024, 512, 256};
  const int glc8[6] = {5, 6, 7, 6, 5, 4};  // log2(Cout/8)

  // enc layer 1 (all batches) -> bufA [M_TOTAL,256]
  dim3 e1grid((NV * 256 + 255) / 256, NB);
  enc1_kernel<<<e1grid, 256, 0, stream>>>(vertices, enc_W1, encc, bufA);
  // enc layer 2 -> bufB [M_TOTAL,128]
  launch_gemm(bufA, wt[0], enc_b2, nullptr, bufB, 128, 256, 1 | 2, stream);

  unsigned short* x = bufB;
  unsigned short* h = bufA;
  for (int i = 0; i < 6; ++i) {
    // hs = (x @ gW) * dinv[row]   (no bias/relu)
    launch_gemm(x, wt[1 + i], nullptr, drep, h, gout[i], gin[i], 4, stream);
    int total8 = NV * (gout[i] / 8);
    dim3 ggrid((total8 + 255) / 256, NB);
    gcn_gather_kernel<<<ggrid, 256, 0, stream>>>(
        (const uint4*)h, gb[i], dinv, rowp, esrc, (uint4*)x, glc8[i]);
  }
  // head
  launch_gemm(x, wt[7], hb1, nullptr, h, 128, 128, 1 | 2, stream);  // bufA [M_TOTAL,128]
  launch_gemm(h, wt[8], hb2, nullptr, x, 64, 128, 1 | 2, stream);   // bufB [M_TOTAL,64]
  dim3 hgrid((NV * 3 + 255) / 256, NB);
  head3_kernel<<<hgrid, 256, 0, stream>>>(x, hW3, hb3, vertices, (float*)d_out);
}